// Round 3
// baseline (232.272 us; speedup 1.0000x reference)
//
#include <hip/hip_runtime.h>

// Sizes (fixed by the problem)
#define B_ 8192
#define T_ 256
#define I_ 28
#define H_ 10

// d_out layout: [B*T*H] output, then [2*B*H] h_final
#define OUT_MAIN (B_ * T_ * H_)   // 20971520
#define BH (B_ * H_)              // 81920

__device__ __forceinline__ float fast_tanh(float x) {
    // tanh(x) = 1 - 2/(exp(2x)+1); exp(2x) = exp2(x * 2*log2(e))
    float e = __builtin_amdgcn_exp2f(x * 2.885390081777927f);
    return __builtin_fmaf(-2.0f, __builtin_amdgcn_rcpf(e + 1.0f), 1.0f);
}

// ---------------- K1: xw0[b][t][u] = sum_i x[b][t][i] * Wih0[u][i] + (bih0[u]+bhh0[u])
// Memory-bound, ~roofline. 2 rows (b,t) per thread, weights in LDS.
__global__ __launch_bounds__(256) void rnn_k1(
        const float* __restrict__ x, const float* __restrict__ Wih0,
        const float* __restrict__ bih0, const float* __restrict__ bhh0,
        float* __restrict__ xw0) {
    __shared__ float Wl[H_ * I_];
    __shared__ float bl[H_];
    int tid = threadIdx.x;
    for (int i = tid; i < H_ * I_; i += 256) Wl[i] = Wih0[i];  // 280 > 256: loop!
    if (tid < H_) bl[tid] = bih0[tid] + bhh0[tid];
    __syncthreads();

    long row0 = ((long)blockIdx.x * 256 + tid) * 2;
    const float* xr = x + row0 * I_;
    float xa[I_], xb[I_];
#pragma unroll
    for (int i = 0; i < 7; i++) {
        float4 va = ((const float4*)xr)[i];
        float4 vb = ((const float4*)(xr + I_))[i];
        xa[4*i+0] = va.x; xa[4*i+1] = va.y; xa[4*i+2] = va.z; xa[4*i+3] = va.w;
        xb[4*i+0] = vb.x; xb[4*i+1] = vb.y; xb[4*i+2] = vb.z; xb[4*i+3] = vb.w;
    }
    float oa[H_], ob[H_];
#pragma unroll
    for (int u = 0; u < H_; u++) {
        float s0 = bl[u], s1 = bl[u];
#pragma unroll
        for (int i = 0; i < I_; i++) {
            float w = Wl[u * I_ + i];
            s0 = __builtin_fmaf(xa[i], w, s0);
            s1 = __builtin_fmaf(xb[i], w, s1);
        }
        oa[u] = s0; ob[u] = s1;
    }
    float* o = xw0 + row0 * H_;
#pragma unroll
    for (int i = 0; i < 5; i++) {
        ((float2*)o)[i]        = make_float2(oa[2*i], oa[2*i+1]);
        ((float2*)(o + H_))[i] = make_float2(ob[2*i], ob[2*i+1]);
    }
}

// ---------------- K2: recurrent pass, DPP-ring (zero LDS/DS ops).
// 16 lanes per batch; lane j owns unit j (H zero-padded to 16; pad lanes compute 0).
// Dot products: a += rot<s>(h) * w[s], rot<s> = v_mov_b32_dpp row_ror:s
// (dst lane j <- src lane (j-s)&15), w[s] = W[j][(j-s)&15] preloaded per lane.
// All rotations source the ORIGINAL h (ILP); no cross-lane memory ops at all.
// 131072 threads = 2048 waves = 2 waves/SIMD.

template <int S>
__device__ __forceinline__ float rotf(float v) {
    return __int_as_float(__builtin_amdgcn_mov_dpp(
        __float_as_int(v), 0x120 + S, 0xF, 0xF, true));  // row_ror:S
}

template <int S>
__device__ __forceinline__ void ring16(float& a, float v, const float (&w)[16]) {
    a = __builtin_fmaf(rotf<S>(v), w[S], a);
    if constexpr (S < 15) ring16<S + 1>(a, v, w);
}

__global__ __launch_bounds__(256) void rnn_k2(
        float* __restrict__ buf,            // d_out: xw0 in, output overwrites in place
        const float* __restrict__ h0in,     // [2][B][H]
        const float* __restrict__ Whh0, const float* __restrict__ Wih1,
        const float* __restrict__ Whh1,
        const float* __restrict__ bih1, const float* __restrict__ bhh1,
        float* __restrict__ hfin) {         // d_out + OUT_MAIN
    int id = blockIdx.x * 256 + threadIdx.x;
    int b = id >> 4;
    int j = id & 15;
    bool act = (j < 10);

    // Per-lane rotated weight rows, zero-padded to 16
    float w0[16], wi[16], wh[16];
#pragma unroll
    for (int s = 0; s < 16; s++) {
        int k = (j - s) & 15;
        bool ok = act && (k < 10);
        w0[s] = ok ? Whh0[j * H_ + k] : 0.f;
        wi[s] = ok ? Wih1[j * H_ + k] : 0.f;
        wh[s] = ok ? Whh1[j * H_ + k] : 0.f;
    }
    float bj  = act ? (bih1[j] + bhh1[j]) : 0.f;
    float h0v = act ? h0in[b * H_ + j] : 0.f;
    float h1v = act ? h0in[BH + b * H_ + j] : 0.f;

    float* base = buf + (long)b * (T_ * H_);
    float xb[4];
#pragma unroll
    for (int q = 0; q < 4; q++) xb[q] = act ? base[q * H_ + j] : 0.f;

    for (int t = 0; t < T_; t += 4) {
#pragma unroll
        for (int q = 0; q < 4; q++) {
            int tc = t + q;
            float a = xb[q];
            // prefetch 4 steps ahead (reads lead in-place writes by 4)
            if (tc + 4 < T_) xb[q] = act ? base[(tc + 4) * H_ + j] : 0.f;
            // layer 0: a = xw0 + Whh0 . h0
            a = __builtin_fmaf(h0v, w0[0], a);
            ring16<1>(a, h0v, w0);
            float h0n = fast_tanh(a);
            // layer 1: c = b1 + Wih1 . h0_new + Whh1 . h1_old
            float c = bj;
            c = __builtin_fmaf(h0n, wi[0], c);
            c = __builtin_fmaf(h1v, wh[0], c);
            ring16<1>(c, h0n, wi);
            ring16<1>(c, h1v, wh);
            float h1n = fast_tanh(c);
            if (act) base[tc * H_ + j] = h1n;
            h0v = h0n; h1v = h1n;
        }
    }
    if (act) {
        hfin[b * H_ + j]      = h0v;
        hfin[BH + b * H_ + j] = h1v;
    }
}

extern "C" void kernel_launch(void* const* d_in, const int* in_sizes, int n_in,
                              void* d_out, int out_size, void* d_ws, size_t ws_size,
                              hipStream_t stream) {
    const float* x     = (const float*)d_in[0];
    const float* h0in  = (const float*)d_in[1];
    const float* Wih0  = (const float*)d_in[2];
    const float* Whh0  = (const float*)d_in[3];
    const float* bih0  = (const float*)d_in[4];
    const float* bhh0  = (const float*)d_in[5];
    const float* Wih1  = (const float*)d_in[6];
    const float* Whh1  = (const float*)d_in[7];
    const float* bih1  = (const float*)d_in[8];
    const float* bhh1  = (const float*)d_in[9];
    float* out = (float*)d_out;

    // K1: xw0 into d_out main region
    rnn_k1<<<dim3((B_ * T_) / 512), dim3(256), 0, stream>>>(x, Wih0, bih0, bhh0, out);
    // K2: 16 lanes/batch -> 131072 threads -> 512 blocks
    rnn_k2<<<dim3(512), dim3(256), 0, stream>>>(out, h0in, Whh0, Wih1, Whh1,
                                                bih1, bhh1, out + OUT_MAIN);
}

// Round 4
// 202.092 us; speedup vs baseline: 1.1493x; 1.1493x over previous
//
#include <hip/hip_runtime.h>

// Sizes (fixed by the problem)
#define B_ 8192
#define T_ 256
#define I_ 28
#define H_ 10

// d_out layout: [B*T*H] output, then [2*B*H] h_final
#define OUT_MAIN (B_ * T_ * H_)   // 20971520
#define BH (B_ * H_)              // 81920

__device__ __forceinline__ float fast_tanh(float x) {
    // tanh(x) = 1 - 2/(exp(2x)+1); exp(2x) = exp2(x * 2*log2(e))
    float e = __builtin_amdgcn_exp2f(x * 2.885390081777927f);
    return __builtin_fmaf(-2.0f, __builtin_amdgcn_rcpf(e + 1.0f), 1.0f);
}

// ---------------- K1: xw0[b][t][u] = sum_i x[b][t][i] * Wih0[u][i] + (bih0[u]+bhh0[u])
// Memory-bound, ~roofline (~52 us, ~90% HBM). 2 rows (b,t) per thread, weights in LDS.
__global__ __launch_bounds__(256) void rnn_k1(
        const float* __restrict__ x, const float* __restrict__ Wih0,
        const float* __restrict__ bih0, const float* __restrict__ bhh0,
        float* __restrict__ xw0) {
    __shared__ float Wl[H_ * I_];
    __shared__ float bl[H_];
    int tid = threadIdx.x;
    for (int i = tid; i < H_ * I_; i += 256) Wl[i] = Wih0[i];  // 280 > 256: loop!
    if (tid < H_) bl[tid] = bih0[tid] + bhh0[tid];
    __syncthreads();

    long row0 = ((long)blockIdx.x * 256 + tid) * 2;
    const float* xr = x + row0 * I_;
    float xa[I_], xb[I_];
#pragma unroll
    for (int i = 0; i < 7; i++) {
        float4 va = ((const float4*)xr)[i];
        float4 vb = ((const float4*)(xr + I_))[i];
        xa[4*i+0] = va.x; xa[4*i+1] = va.y; xa[4*i+2] = va.z; xa[4*i+3] = va.w;
        xb[4*i+0] = vb.x; xb[4*i+1] = vb.y; xb[4*i+2] = vb.z; xb[4*i+3] = vb.w;
    }
    float oa[H_], ob[H_];
#pragma unroll
    for (int u = 0; u < H_; u++) {
        float s0 = bl[u], s1 = bl[u];
#pragma unroll
        for (int i = 0; i < I_; i++) {
            float w = Wl[u * I_ + i];
            s0 = __builtin_fmaf(xa[i], w, s0);
            s1 = __builtin_fmaf(xb[i], w, s1);
        }
        oa[u] = s0; ob[u] = s1;
    }
    float* o = xw0 + row0 * H_;
#pragma unroll
    for (int i = 0; i < 5; i++) {
        ((float2*)o)[i]        = make_float2(oa[2*i], oa[2*i+1]);
        ((float2*)(o + H_))[i] = make_float2(ob[2*i], ob[2*i+1]);
    }
}

// ---------------- K2: recurrent pass, DPP-ring (zero LDS/DS ops).
// 16 lanes per batch; lane j owns unit j (H padded to 16; pad lanes compute 0).
// Round-3 post-mortem: VGPR_Count=36 -> allocator rematerialized the 48
// loop-invariant weight loads INSIDE the t-loop (~48 cache loads/step on the
// dependent path -> 180us). Fix: __launch_bounds__(256,2) raises the VGPR
// budget to 256/wave (we launch exactly 2 waves/SIMD), and the weights are
// 48 NAMED const float scalars so no array heuristic can demote them.

template <int S>
__device__ __forceinline__ float rotf(float v) {
    return __int_as_float(__builtin_amdgcn_mov_dpp(
        __float_as_int(v), 0x120 + S, 0xF, 0xF, true));  // row_ror:S  (validated r3)
}

// named weight slot S of ring P from SRC (rotated row: P_S = W[j][(j-S)&15], 0 if pad)
#define WINIT(P, SRC, S) \
    const float P##_##S = ((act) && (((j - (S)) & 15) < H_)) \
        ? SRC[j * H_ + ((j - (S)) & 15)] : 0.f;
#define WALL(P, SRC) \
    WINIT(P, SRC, 0)  WINIT(P, SRC, 1)  WINIT(P, SRC, 2)  WINIT(P, SRC, 3)  \
    WINIT(P, SRC, 4)  WINIT(P, SRC, 5)  WINIT(P, SRC, 6)  WINIT(P, SRC, 7)  \
    WINIT(P, SRC, 8)  WINIT(P, SRC, 9)  WINIT(P, SRC, 10) WINIT(P, SRC, 11) \
    WINIT(P, SRC, 12) WINIT(P, SRC, 13) WINIT(P, SRC, 14) WINIT(P, SRC, 15)

#define R1(acc, v, P, S) acc = __builtin_fmaf(rotf<S>(v), P##_##S, acc);
// chain slots 1..7 (acc seeded with slot 0)
#define CH_LO(acc, v, P) \
    R1(acc, v, P, 1) R1(acc, v, P, 2) R1(acc, v, P, 3) R1(acc, v, P, 4) \
    R1(acc, v, P, 5) R1(acc, v, P, 6) R1(acc, v, P, 7)
// chain slots 9..15 (acc seeded with slot 8)
#define CH_HI(acc, v, P) \
    R1(acc, v, P, 9)  R1(acc, v, P, 10) R1(acc, v, P, 11) R1(acc, v, P, 12) \
    R1(acc, v, P, 13) R1(acc, v, P, 14) R1(acc, v, P, 15)

__global__ __launch_bounds__(256, 2) void rnn_k2(
        float* __restrict__ buf,            // d_out: xw0 in, output overwrites in place
        const float* __restrict__ h0in,     // [2][B][H]
        const float* __restrict__ Whh0, const float* __restrict__ Wih1,
        const float* __restrict__ Whh1,
        const float* __restrict__ bih1, const float* __restrict__ bhh1,
        float* __restrict__ hfin) {         // d_out + OUT_MAIN
    int id = blockIdx.x * 256 + threadIdx.x;
    int b = id >> 4;
    int j = id & 15;
    bool act = (j < H_);

    WALL(w0, Whh0)
    WALL(wi, Wih1)
    WALL(wh, Whh1)
    float bj  = act ? (bih1[j] + bhh1[j]) : 0.f;
    float h0v = act ? h0in[b * H_ + j] : 0.f;
    float h1v = act ? h0in[BH + b * H_ + j] : 0.f;

    float* base = buf + (long)b * (T_ * H_);
    float xb[4];
#pragma unroll
    for (int q = 0; q < 4; q++) xb[q] = act ? base[q * H_ + j] : 0.f;

    for (int t = 0; t < T_; t += 4) {
#pragma unroll
        for (int q = 0; q < 4; q++) {
            int tc = t + q;
            // prefetch 4 steps ahead (reads lead in-place writes by 4)
            float xnext = (tc + 4 < T_ && act) ? base[(tc + 4) * H_ + j] : 0.f;
            // layer 0: a = xw0 + Whh0 . h0   (2 chains of 8)
            float aA = __builtin_fmaf(h0v, w0_0, xb[q]);
            CH_LO(aA, h0v, w0)
            float aB = rotf<8>(h0v) * w0_8;
            CH_HI(aB, h0v, w0)
            float h0n = fast_tanh(aA + aB);
            // layer 1: c = b1 + Wih1 . h0n + Whh1 . h1   (4 chains of 8)
            float cA = __builtin_fmaf(h0n, wi_0, bj);
            CH_LO(cA, h0n, wi)
            float cB = rotf<8>(h0n) * wi_8;
            CH_HI(cB, h0n, wi)
            float cC = h1v * wh_0;
            CH_LO(cC, h1v, wh)
            float cD = rotf<8>(h1v) * wh_8;
            CH_HI(cD, h1v, wh)
            float h1n = fast_tanh((cA + cB) + (cC + cD));
            if (act) base[tc * H_ + j] = h1n;
            xb[q] = xnext;
            h0v = h0n; h1v = h1n;
        }
    }
    if (act) {
        hfin[b * H_ + j]      = h0v;
        hfin[BH + b * H_ + j] = h1v;
    }
}

extern "C" void kernel_launch(void* const* d_in, const int* in_sizes, int n_in,
                              void* d_out, int out_size, void* d_ws, size_t ws_size,
                              hipStream_t stream) {
    const float* x     = (const float*)d_in[0];
    const float* h0in  = (const float*)d_in[1];
    const float* Wih0  = (const float*)d_in[2];
    const float* Whh0  = (const float*)d_in[3];
    const float* bih0  = (const float*)d_in[4];
    const float* bhh0  = (const float*)d_in[5];
    const float* Wih1  = (const float*)d_in[6];
    const float* Whh1  = (const float*)d_in[7];
    const float* bih1  = (const float*)d_in[8];
    const float* bhh1  = (const float*)d_in[9];
    float* out = (float*)d_out;

    // K1: xw0 into d_out main region
    rnn_k1<<<dim3((B_ * T_) / 512), dim3(256), 0, stream>>>(x, Wih0, bih0, bhh0, out);
    // K2: 16 lanes/batch -> 131072 threads -> 512 blocks (2 waves/SIMD)
    rnn_k2<<<dim3(512), dim3(256), 0, stream>>>(out, h0in, Whh0, Wih1, Whh1,
                                                bih1, bhh1, out + OUT_MAIN);
}